// Round 1
// baseline (413.607 us; speedup 1.0000x reference)
//
#include <hip/hip_runtime.h>
#include <hip/hip_bf16.h>

#define NN 100000   // nodes
#define NE 50000    // edges
#define NZ 800000   // incidences
#define D  128

// ---------------- GEMM: x = x0 @ W.T + b ----------------
// tile: 128 rows x 128 cols per block; K chunked by 32.
// per thread: 4 rows x 16 cols (4 float4 strided by 32 cols).
__global__ __launch_bounds__(256) void unisage_gemm(const float* __restrict__ x0,
                                                    const float* __restrict__ W,
                                                    const float* __restrict__ bias,
                                                    float* __restrict__ x) {
  __shared__ float xs[32][132];   // [k][row]
  __shared__ float wsh[32][132];  // [k][col]
  const int t = threadIdx.x;
  const int row0 = blockIdx.x * 128;
  const int rg = t >> 3;   // 0..31
  const int cg = t & 7;    // 0..7
  const int r0 = rg * 4;
  const int c0 = cg * 4;
  float acc[4][4][4] = {};  // [row i][col-block m][col j]

  for (int kc = 0; kc < 4; ++kc) {
    const int k0 = kc * 32;
    __syncthreads();
#pragma unroll
    for (int p = 0; p < 4; ++p) {
      int q = p * 256 + t;      // float4 index within tile
      int row = q >> 3;         // 0..127
      int kk = (q & 7) * 4;     // 0..28
      int gr = row0 + row;
      float4 v = make_float4(0.f, 0.f, 0.f, 0.f);
      if (gr < NN) v = *(const float4*)(x0 + (size_t)gr * D + k0 + kk);
      xs[kk + 0][row] = v.x; xs[kk + 1][row] = v.y;
      xs[kk + 2][row] = v.z; xs[kk + 3][row] = v.w;
      float4 wv = *(const float4*)(W + (size_t)row * D + k0 + kk);
      wsh[kk + 0][row] = wv.x; wsh[kk + 1][row] = wv.y;
      wsh[kk + 2][row] = wv.z; wsh[kk + 3][row] = wv.w;
    }
    __syncthreads();
#pragma unroll
    for (int kk = 0; kk < 32; ++kk) {
      float4 xv4 = *(const float4*)&xs[kk][r0];
      float xv[4] = {xv4.x, xv4.y, xv4.z, xv4.w};
#pragma unroll
      for (int m = 0; m < 4; ++m) {
        float4 wv4 = *(const float4*)&wsh[kk][c0 + 32 * m];
        float wv[4] = {wv4.x, wv4.y, wv4.z, wv4.w};
#pragma unroll
        for (int i = 0; i < 4; ++i)
#pragma unroll
          for (int j = 0; j < 4; ++j)
            acc[i][m][j] += xv[i] * wv[j];
      }
    }
  }
#pragma unroll
  for (int m = 0; m < 4; ++m) {
    float4 bv = *(const float4*)(bias + c0 + 32 * m);
#pragma unroll
    for (int i = 0; i < 4; ++i) {
      int gr = row0 + r0 + i;
      if (gr < NN) {
        float4 o;
        o.x = acc[i][m][0] + bv.x;
        o.y = acc[i][m][1] + bv.y;
        o.z = acc[i][m][2] + bv.z;
        o.w = acc[i][m][3] + bv.w;
        *(float4*)(x + (size_t)gr * D + c0 + 32 * m) = o;
      }
    }
  }
}

// ---------------- CSR build ----------------
__global__ void unisage_hist(const int* __restrict__ nid, const int* __restrict__ eid,
                             int* __restrict__ cnt) {
  int i = blockIdx.x * 256 + threadIdx.x;
  if (i >= NZ) return;
  atomicAdd(&cnt[eid[i]], 1);
  atomicAdd(&cnt[NE + nid[i]], 1);
}

__global__ void unisage_scan_k1(const int* __restrict__ in, int* __restrict__ bsum, int n) {
  __shared__ int sh[256];
  int t = threadIdx.x;
  int base = blockIdx.x * 1024 + t * 4;
  int s = 0;
#pragma unroll
  for (int j = 0; j < 4; ++j)
    if (base + j < n) s += in[base + j];
  sh[t] = s;
  __syncthreads();
  for (int o = 128; o > 0; o >>= 1) {
    if (t < o) sh[t] += sh[t + o];
    __syncthreads();
  }
  if (t == 0) bsum[blockIdx.x] = sh[0];
}

__global__ void unisage_scan_k2(const int* __restrict__ bsum, int* __restrict__ bsumx, int nb) {
  if (threadIdx.x == 0 && blockIdx.x == 0) {
    int acc = 0;
    for (int i = 0; i < nb; ++i) { int v = bsum[i]; bsumx[i] = acc; acc += v; }
  }
}

__global__ void unisage_scan_k3(const int* __restrict__ in, const int* __restrict__ bsumx,
                                int* __restrict__ out, int n) {
  __shared__ int sh[256];
  int t = threadIdx.x;
  int base = blockIdx.x * 1024 + t * 4;
  int v[4];
#pragma unroll
  for (int j = 0; j < 4; ++j) v[j] = (base + j < n) ? in[base + j] : 0;
  int tsum = v[0] + v[1] + v[2] + v[3];
  sh[t] = tsum;
  __syncthreads();
  for (int o = 1; o < 256; o <<= 1) {
    int add = (t >= o) ? sh[t - o] : 0;
    __syncthreads();
    sh[t] += add;
    __syncthreads();
  }
  int run = sh[t] - tsum + bsumx[blockIdx.x];
#pragma unroll
  for (int j = 0; j < 4; ++j) {
    if (base + j < n) out[base + j] = run;
    run += v[j];
  }
}

// fill: off[] (exclusive scan) is used as atomic cursor; afterwards off[s] = segment END.
__global__ void unisage_fill(const int* __restrict__ nid, const int* __restrict__ eid,
                             int* __restrict__ off, int* __restrict__ csr_e,
                             int* __restrict__ csr_n) {
  int i = blockIdx.x * 256 + threadIdx.x;
  if (i >= NZ) return;
  int e = eid[i], v = nid[i];
  int pe = atomicAdd(&off[e], 1);
  csr_e[pe] = v;
  int pn = atomicAdd(&off[NE + v], 1) - NZ;
  csr_n[pn] = e;
}

// ---------------- segment aggregations (one 64-lane wave per segment) ----------------
__global__ void unisage_edge_agg(const float* __restrict__ x, const int* __restrict__ csr_e,
                                 const int* __restrict__ off, const int* __restrict__ cnt,
                                 float* __restrict__ m01) {
  int w = (blockIdx.x * 256 + threadIdx.x) >> 6;  // edge id
  int lane = threadIdx.x & 63;
  if (w >= NE) return;
  int end = off[w];
  int deg = cnt[w];
  int beg = end - deg;
  float2 acc = make_float2(0.f, 0.f);
  for (int base = beg; base < end; base += 64) {
    int m = min(64, end - base);
    int idx = (lane < m) ? csr_e[base + lane] : 0;
    for (int j = 0; j < m; ++j) {
      int node = __shfl(idx, j, 64);
      float2 v = *(const float2*)(x + (size_t)node * D + lane * 2);
      acc.x += v.x; acc.y += v.y;
    }
  }
  *(float2*)(m01 + (size_t)w * D + lane * 2) = acc;
}

__global__ void unisage_node_agg(const float* __restrict__ x, const float* __restrict__ m01,
                                 const int* __restrict__ csr_n, const int* __restrict__ off,
                                 const int* __restrict__ cnt, float* __restrict__ out) {
  int w = (blockIdx.x * 256 + threadIdx.x) >> 6;  // node id
  int lane = threadIdx.x & 63;
  if (w >= NN) return;
  int end = off[NE + w] - NZ;
  int deg = cnt[NE + w];
  int beg = end - deg;
  float2 acc = make_float2(0.f, 0.f);
  for (int base = beg; base < end; base += 64) {
    int m = min(64, end - base);
    int idx = (lane < m) ? csr_n[base + lane] : 0;
    for (int j = 0; j < m; ++j) {
      int e = __shfl(idx, j, 64);
      float2 v = *(const float2*)(m01 + (size_t)e * D + lane * 2);
      acc.x += v.x; acc.y += v.y;
    }
  }
  float inv = 1.0f / fmaxf((float)deg, 1.0f);
  float2 xr = *(const float2*)(x + (size_t)w * D + lane * 2);
  float2 o;
  o.x = xr.x + acc.x * inv;
  o.y = xr.y + acc.y * inv;
  *(float2*)(out + (size_t)w * D + lane * 2) = o;
}

extern "C" void kernel_launch(void* const* d_in, const int* in_sizes, int n_in,
                              void* d_out, int out_size, void* d_ws, size_t ws_size,
                              hipStream_t stream) {
  const float* x0   = (const float*)d_in[0];
  const float* W    = (const float*)d_in[1];
  const float* bias = (const float*)d_in[2];
  const int* nid    = (const int*)d_in[3];
  const int* eid    = (const int*)d_in[4];
  float* out = (float*)d_out;

  // workspace layout
  float* x   = (float*)d_ws;                 // NN*D floats   (51.2 MB)
  float* m01 = x + (size_t)NN * D;           // NE*D floats   (25.6 MB)
  int* cnt   = (int*)(m01 + (size_t)NE * D); // NE+NN = 150000
  int* off   = cnt + 150016;                 // 150000
  int* csr_e = off + 150016;                 // NZ
  int* csr_n = csr_e + NZ;                   // NZ
  int* bsum  = csr_n + NZ;                   // 256
  int* bsumx = bsum + 256;                   // 256

  hipMemsetAsync(cnt, 0, 150000 * sizeof(int), stream);

  unisage_gemm<<<(NN + 127) / 128, 256, 0, stream>>>(x0, W, bias, x);

  unisage_hist<<<NZ / 256, 256, 0, stream>>>(nid, eid, cnt);

  const int n_comb = NE + NN;             // 150000
  const int nb = (n_comb + 1023) / 1024;  // 147
  unisage_scan_k1<<<nb, 256, 0, stream>>>(cnt, bsum, n_comb);
  unisage_scan_k2<<<1, 64, 0, stream>>>(bsum, bsumx, nb);
  unisage_scan_k3<<<nb, 256, 0, stream>>>(cnt, bsumx, off, n_comb);

  unisage_fill<<<NZ / 256, 256, 0, stream>>>(nid, eid, off, csr_e, csr_n);

  unisage_edge_agg<<<(NE * 64) / 256, 256, 0, stream>>>(x, csr_e, off, cnt, m01);
  unisage_node_agg<<<(NN * 64) / 256, 256, 0, stream>>>(x, m01, csr_n, off, cnt, out);
}

// Round 2
// 254.024 us; speedup vs baseline: 1.6282x; 1.6282x over previous
//
#include <hip/hip_runtime.h>
#include <hip/hip_bf16.h>

#define NN 100000   // nodes
#define NE 50000    // edges
#define NZ 800000   // incidences
#define D  128
#define NSEG (NE + NN)   // 150000
#define FILL_P 8         // fill passes (segment-range partitions)
#define FILL_B 3125      // blocks per pass = NZ/256

static __device__ __forceinline__ unsigned short f2bf(float f) {
  union { float f; unsigned u; } v; v.f = f;
  unsigned r = (v.u + 0x7FFFu + ((v.u >> 16) & 1u)) >> 16;  // RNE
  return (unsigned short)r;
}
static __device__ __forceinline__ float bf2f(unsigned short h) {
  union { unsigned u; float f; } v; v.u = ((unsigned)h) << 16;
  return v.f;
}

// ---------------- GEMM: xb = bf16(x0 @ W.T + b) ----------------
__global__ __launch_bounds__(256) void unisage_gemm(const float* __restrict__ x0,
                                                    const float* __restrict__ W,
                                                    const float* __restrict__ bias,
                                                    unsigned short* __restrict__ xb) {
  __shared__ float xs[32][132];   // [k][row]
  __shared__ float wsh[32][132];  // [k][col]
  const int t = threadIdx.x;
  const int row0 = blockIdx.x * 128;
  const int rg = t >> 3;   // 0..31
  const int cg = t & 7;    // 0..7
  const int r0 = rg * 4;
  const int c0 = cg * 4;
  float acc[4][4][4] = {};  // [row i][col-block m][col j]

  for (int kc = 0; kc < 4; ++kc) {
    const int k0 = kc * 32;
    __syncthreads();
#pragma unroll
    for (int p = 0; p < 4; ++p) {
      int q = p * 256 + t;
      int row = q >> 3;
      int kk = (q & 7) * 4;
      int gr = row0 + row;
      float4 v = make_float4(0.f, 0.f, 0.f, 0.f);
      if (gr < NN) v = *(const float4*)(x0 + (size_t)gr * D + k0 + kk);
      xs[kk + 0][row] = v.x; xs[kk + 1][row] = v.y;
      xs[kk + 2][row] = v.z; xs[kk + 3][row] = v.w;
      float4 wv = *(const float4*)(W + (size_t)row * D + k0 + kk);
      wsh[kk + 0][row] = wv.x; wsh[kk + 1][row] = wv.y;
      wsh[kk + 2][row] = wv.z; wsh[kk + 3][row] = wv.w;
    }
    __syncthreads();
#pragma unroll
    for (int kk = 0; kk < 32; ++kk) {
      float4 xv4 = *(const float4*)&xs[kk][r0];
      float xv[4] = {xv4.x, xv4.y, xv4.z, xv4.w};
#pragma unroll
      for (int m = 0; m < 4; ++m) {
        float4 wv4 = *(const float4*)&wsh[kk][c0 + 32 * m];
        float wv[4] = {wv4.x, wv4.y, wv4.z, wv4.w};
#pragma unroll
        for (int i = 0; i < 4; ++i)
#pragma unroll
          for (int j = 0; j < 4; ++j)
            acc[i][m][j] += xv[i] * wv[j];
      }
    }
  }
#pragma unroll
  for (int m = 0; m < 4; ++m) {
    float4 bv = *(const float4*)(bias + c0 + 32 * m);
#pragma unroll
    for (int i = 0; i < 4; ++i) {
      int gr = row0 + r0 + i;
      if (gr < NN) {
        ushort4 o;
        o.x = f2bf(acc[i][m][0] + bv.x);
        o.y = f2bf(acc[i][m][1] + bv.y);
        o.z = f2bf(acc[i][m][2] + bv.z);
        o.w = f2bf(acc[i][m][3] + bv.w);
        *(ushort4*)(xb + (size_t)gr * D + c0 + 32 * m) = o;
      }
    }
  }
}

// ---------------- histogram + rank (the only atomics in the pipeline) ----------------
__global__ void unisage_hist_rank(const int* __restrict__ nid, const int* __restrict__ eid,
                                  int* __restrict__ cnt, unsigned int* __restrict__ rank) {
  int i = blockIdx.x * 256 + threadIdx.x;
  if (i >= NZ) return;
  int e = eid[i], v = nid[i];
  unsigned re = (unsigned)atomicAdd(&cnt[e], 1);
  unsigned rn = (unsigned)atomicAdd(&cnt[NE + v], 1);
  rank[i] = (re & 0xffffu) | (rn << 16);
}

// ---------------- scans ----------------
__global__ void unisage_scan_k1(const int* __restrict__ in, int* __restrict__ bsum, int n) {
  __shared__ int sh[256];
  int t = threadIdx.x;
  int base = blockIdx.x * 1024 + t * 4;
  int s = 0;
#pragma unroll
  for (int j = 0; j < 4; ++j)
    if (base + j < n) s += in[base + j];
  sh[t] = s;
  __syncthreads();
  for (int o = 128; o > 0; o >>= 1) {
    if (t < o) sh[t] += sh[t + o];
    __syncthreads();
  }
  if (t == 0) bsum[blockIdx.x] = sh[0];
}

// single-block Hillis-Steele exclusive scan of nb (<=256) block sums
__global__ void unisage_scan_k2(const int* __restrict__ bsum, int* __restrict__ bsumx, int nb) {
  __shared__ int sh[256];
  int t = threadIdx.x;
  int v = (t < nb) ? bsum[t] : 0;
  sh[t] = v;
  __syncthreads();
  for (int o = 1; o < 256; o <<= 1) {
    int add = (t >= o) ? sh[t - o] : 0;
    __syncthreads();
    sh[t] += add;
    __syncthreads();
  }
  if (t < nb) bsumx[t] = sh[t] - v;  // exclusive
}

__global__ void unisage_scan_k3(const int* __restrict__ in, const int* __restrict__ bsumx,
                                int* __restrict__ out, int n) {
  __shared__ int sh[256];
  int t = threadIdx.x;
  int base = blockIdx.x * 1024 + t * 4;
  int v[4];
#pragma unroll
  for (int j = 0; j < 4; ++j) v[j] = (base + j < n) ? in[base + j] : 0;
  int tsum = v[0] + v[1] + v[2] + v[3];
  sh[t] = tsum;
  __syncthreads();
  for (int o = 1; o < 256; o <<= 1) {
    int add = (t >= o) ? sh[t - o] : 0;
    __syncthreads();
    sh[t] += add;
    __syncthreads();
  }
  int run = sh[t] - tsum + bsumx[blockIdx.x];
#pragma unroll
  for (int j = 0; j < 4; ++j) {
    if (base + j < n) out[base + j] = run;
    run += v[j];
  }
}

// ---------------- fill: atomic-free, pass-partitioned by segment range ----------------
// pass p only writes CSR entries whose segment id is in [p*R, (p+1)*R) -> the scattered
// stores of one pass land in a ~1MB L2-resident region and accumulate full lines.
__global__ void unisage_fill(const int* __restrict__ nid, const int* __restrict__ eid,
                             const unsigned int* __restrict__ rank,
                             const int* __restrict__ off,
                             int* __restrict__ csr_e, int* __restrict__ csr_n) {
  const int R = (NSEG + FILL_P - 1) / FILL_P;  // 18750
  int pass = blockIdx.x / FILL_B;
  int i = (blockIdx.x % FILL_B) * 256 + threadIdx.x;
  if (i >= NZ) return;
  int lo = pass * R, hi = lo + R;
  int e = eid[i], v = nid[i];
  unsigned r = rank[i];
  if (e >= lo && e < hi) csr_e[off[e] + (int)(r & 0xffffu)] = v;
  int s = NE + v;
  if (s >= lo && s < hi) csr_n[off[s] + (int)(r >> 16) - NZ] = e;
}

// ---------------- segment aggregations (one 64-lane wave per segment, bf16 gather) ----
__global__ void unisage_edge_agg(const unsigned short* __restrict__ xb,
                                 const int* __restrict__ csr_e,
                                 const int* __restrict__ off, const int* __restrict__ cnt,
                                 unsigned short* __restrict__ m01b) {
  int w = (blockIdx.x * 256 + threadIdx.x) >> 6;  // edge id
  int lane = threadIdx.x & 63;
  if (w >= NE) return;
  int beg = off[w];
  int end = beg + cnt[w];
  float ax = 0.f, ay = 0.f;
  for (int base = beg; base < end; base += 64) {
    int m = min(64, end - base);
    int idx = (lane < m) ? csr_e[base + lane] : 0;
    int j = 0;
    for (; j + 1 < m; j += 2) {
      int n0 = __shfl(idx, j, 64);
      int n1 = __shfl(idx, j + 1, 64);
      ushort2 a = *(const ushort2*)(xb + (size_t)n0 * D + lane * 2);
      ushort2 b = *(const ushort2*)(xb + (size_t)n1 * D + lane * 2);
      ax += bf2f(a.x) + bf2f(b.x);
      ay += bf2f(a.y) + bf2f(b.y);
    }
    if (j < m) {
      int n0 = __shfl(idx, j, 64);
      ushort2 a = *(const ushort2*)(xb + (size_t)n0 * D + lane * 2);
      ax += bf2f(a.x);
      ay += bf2f(a.y);
    }
  }
  ushort2 o; o.x = f2bf(ax); o.y = f2bf(ay);
  *(ushort2*)(m01b + (size_t)w * D + lane * 2) = o;
}

__global__ void unisage_node_agg(const unsigned short* __restrict__ xb,
                                 const unsigned short* __restrict__ m01b,
                                 const int* __restrict__ csr_n,
                                 const int* __restrict__ off, const int* __restrict__ cnt,
                                 float* __restrict__ out) {
  int w = (blockIdx.x * 256 + threadIdx.x) >> 6;  // node id
  int lane = threadIdx.x & 63;
  if (w >= NN) return;
  int deg = cnt[NE + w];
  int beg = off[NE + w] - NZ;
  int end = beg + deg;
  float ax = 0.f, ay = 0.f;
  for (int base = beg; base < end; base += 64) {
    int m = min(64, end - base);
    int idx = (lane < m) ? csr_n[base + lane] : 0;
    int j = 0;
    for (; j + 1 < m; j += 2) {
      int e0 = __shfl(idx, j, 64);
      int e1 = __shfl(idx, j + 1, 64);
      ushort2 a = *(const ushort2*)(m01b + (size_t)e0 * D + lane * 2);
      ushort2 b = *(const ushort2*)(m01b + (size_t)e1 * D + lane * 2);
      ax += bf2f(a.x) + bf2f(b.x);
      ay += bf2f(a.y) + bf2f(b.y);
    }
    if (j < m) {
      int e0 = __shfl(idx, j, 64);
      ushort2 a = *(const ushort2*)(m01b + (size_t)e0 * D + lane * 2);
      ax += bf2f(a.x);
      ay += bf2f(a.y);
    }
  }
  float inv = 1.0f / fmaxf((float)deg, 1.0f);
  ushort2 xr = *(const ushort2*)(xb + (size_t)w * D + lane * 2);
  float2 o;
  o.x = bf2f(xr.x) + ax * inv;
  o.y = bf2f(xr.y) + ay * inv;
  *(float2*)(out + (size_t)w * D + lane * 2) = o;
}

extern "C" void kernel_launch(void* const* d_in, const int* in_sizes, int n_in,
                              void* d_out, int out_size, void* d_ws, size_t ws_size,
                              hipStream_t stream) {
  const float* x0   = (const float*)d_in[0];
  const float* W    = (const float*)d_in[1];
  const float* bias = (const float*)d_in[2];
  const int* nid    = (const int*)d_in[3];
  const int* eid    = (const int*)d_in[4];
  float* out = (float*)d_out;

  // workspace layout (all 4B-aligned)
  unsigned short* xb   = (unsigned short*)d_ws;           // NN*D bf16 (25.6 MB)
  unsigned short* m01b = xb + (size_t)NN * D;             // NE*D bf16 (12.8 MB)
  int* cnt   = (int*)(m01b + (size_t)NE * D);             // NSEG
  int* off   = cnt + 150016;                              // NSEG
  unsigned int* rank = (unsigned int*)(off + 150016);     // NZ
  int* csr_e = (int*)(rank + NZ);                         // NZ
  int* csr_n = csr_e + NZ;                                // NZ
  int* bsum  = csr_n + NZ;                                // 256
  int* bsumx = bsum + 256;                                // 256

  hipMemsetAsync(cnt, 0, NSEG * sizeof(int), stream);

  unisage_gemm<<<(NN + 127) / 128, 256, 0, stream>>>(x0, W, bias, xb);

  unisage_hist_rank<<<NZ / 256, 256, 0, stream>>>(nid, eid, cnt, rank);

  const int nb = (NSEG + 1023) / 1024;  // 147
  unisage_scan_k1<<<nb, 256, 0, stream>>>(cnt, bsum, NSEG);
  unisage_scan_k2<<<1, 256, 0, stream>>>(bsum, bsumx, nb);
  unisage_scan_k3<<<nb, 256, 0, stream>>>(cnt, bsumx, off, NSEG);

  unisage_fill<<<FILL_P * FILL_B, 256, 0, stream>>>(nid, eid, rank, off, csr_e, csr_n);

  unisage_edge_agg<<<(NE * 64) / 256, 256, 0, stream>>>(xb, csr_e, off, cnt, m01b);
  unisage_node_agg<<<(NN * 64) / 256, 256, 0, stream>>>(xb, m01b, csr_n, off, cnt, out);
}

// Round 3
// 233.071 us; speedup vs baseline: 1.7746x; 1.0899x over previous
//
#include <hip/hip_runtime.h>
#include <hip/hip_bf16.h>

#define NN 100000   // nodes
#define NE 50000    // edges
#define NZ 800000   // incidences
#define D  128
#define NSEG (NE + NN)   // 150000
#define FILL_P 8         // fill passes (segment-range partitions)
#define FILL_B 3125      // blocks per pass = NZ/256

typedef __bf16 bf16x8 __attribute__((ext_vector_type(8)));
typedef float f32x4 __attribute__((ext_vector_type(4)));

static __device__ __forceinline__ unsigned short f2bf(float f) {
  union { float f; unsigned u; } v; v.f = f;
  unsigned r = (v.u + 0x7FFFu + ((v.u >> 16) & 1u)) >> 16;  // RNE
  return (unsigned short)r;
}
static __device__ __forceinline__ float bf2f(unsigned short h) {
  union { unsigned u; float f; } v; v.u = ((unsigned)h) << 16;
  return v.f;
}

// ---------------- GEMM via MFMA: xb = bf16(x0 @ W.T + b) ----------------
// Block: 256 threads = 4 waves, 128 rows (32 rows/wave), all 128 output cols.
// W staged once per block into LDS as bf16, padded stride 136 (conflict-free
// b128 B-fragment reads). A fragments: direct global f32 loads in MFMA lane
// layout (row = lane&15, k = (lane>>4)*8 + j), converted in-register.
__global__ __launch_bounds__(256) void unisage_gemm_mfma(const float* __restrict__ x0,
                                                         const float* __restrict__ W,
                                                         const float* __restrict__ bias,
                                                         unsigned short* __restrict__ xb) {
  __shared__ __bf16 Wl[128][136];
  const int t = threadIdx.x;
#pragma unroll
  for (int i = 0; i < 16; ++i) {
    int idx = i * 1024 + t * 4;   // 16384 floats total, 4 per thread per iter
    int dout = idx >> 7;
    int k = idx & 127;
    float4 wv = *(const float4*)(W + idx);
    Wl[dout][k + 0] = (__bf16)wv.x;
    Wl[dout][k + 1] = (__bf16)wv.y;
    Wl[dout][k + 2] = (__bf16)wv.z;
    Wl[dout][k + 3] = (__bf16)wv.w;
  }
  __syncthreads();

  const int wave = t >> 6;
  const int lane = t & 63;
  const int lr = lane & 15;   // A row / B col / C col within fragment
  const int lg = lane >> 4;   // k-group / C row-group
  const int rowbase = blockIdx.x * 128 + wave * 32;

  f32x4 acc[2][8] = {};  // [row-frag][col-frag]

#pragma unroll
  for (int ks = 0; ks < 4; ++ks) {
    const int k0 = ks * 32 + lg * 8;
    bf16x8 b[8];
#pragma unroll
    for (int cf = 0; cf < 8; ++cf)
      b[cf] = *(const bf16x8*)&Wl[cf * 16 + lr][k0];
#pragma unroll
    for (int rf = 0; rf < 2; ++rf) {
      int row = rowbase + rf * 16 + lr;
      row = row < NN ? row : NN - 1;  // clamp; stores are guarded
      const float* src = x0 + (size_t)row * D + k0;
      float4 f0 = *(const float4*)(src);
      float4 f1 = *(const float4*)(src + 4);
      bf16x8 a;
      a[0] = (__bf16)f0.x; a[1] = (__bf16)f0.y;
      a[2] = (__bf16)f0.z; a[3] = (__bf16)f0.w;
      a[4] = (__bf16)f1.x; a[5] = (__bf16)f1.y;
      a[6] = (__bf16)f1.z; a[7] = (__bf16)f1.w;
#pragma unroll
      for (int cf = 0; cf < 8; ++cf)
        acc[rf][cf] = __builtin_amdgcn_mfma_f32_16x16x32_bf16(a, b[cf], acc[rf][cf], 0, 0, 0);
    }
  }

#pragma unroll
  for (int cf = 0; cf < 8; ++cf) {
    float bv = bias[cf * 16 + lr];
#pragma unroll
    for (int rf = 0; rf < 2; ++rf) {
#pragma unroll
      for (int r = 0; r < 4; ++r) {
        int row = rowbase + rf * 16 + lg * 4 + r;
        if (row < NN)
          xb[(size_t)row * D + cf * 16 + lr] = f2bf(acc[rf][cf][r] + bv);
      }
    }
  }
}

// ---------------- histogram + rank (the only atomics in the pipeline) ----------------
__global__ void unisage_hist_rank(const int* __restrict__ nid, const int* __restrict__ eid,
                                  int* __restrict__ cnt, unsigned int* __restrict__ rank) {
  int i = blockIdx.x * 256 + threadIdx.x;
  if (i >= NZ) return;
  int e = eid[i], v = nid[i];
  unsigned re = (unsigned)atomicAdd(&cnt[e], 1);
  unsigned rn = (unsigned)atomicAdd(&cnt[NE + v], 1);
  rank[i] = (re & 0xffffu) | (rn << 16);
}

// ---------------- scans ----------------
__global__ void unisage_scan_k1(const int* __restrict__ in, int* __restrict__ bsum, int n) {
  __shared__ int sh[256];
  int t = threadIdx.x;
  int base = blockIdx.x * 1024 + t * 4;
  int s = 0;
#pragma unroll
  for (int j = 0; j < 4; ++j)
    if (base + j < n) s += in[base + j];
  sh[t] = s;
  __syncthreads();
  for (int o = 128; o > 0; o >>= 1) {
    if (t < o) sh[t] += sh[t + o];
    __syncthreads();
  }
  if (t == 0) bsum[blockIdx.x] = sh[0];
}

// single-block Hillis-Steele exclusive scan of nb (<=256) block sums
__global__ void unisage_scan_k2(const int* __restrict__ bsum, int* __restrict__ bsumx, int nb) {
  __shared__ int sh[256];
  int t = threadIdx.x;
  int v = (t < nb) ? bsum[t] : 0;
  sh[t] = v;
  __syncthreads();
  for (int o = 1; o < 256; o <<= 1) {
    int add = (t >= o) ? sh[t - o] : 0;
    __syncthreads();
    sh[t] += add;
    __syncthreads();
  }
  if (t < nb) bsumx[t] = sh[t] - v;  // exclusive
}

__global__ void unisage_scan_k3(const int* __restrict__ in, const int* __restrict__ bsumx,
                                int* __restrict__ out, int n) {
  __shared__ int sh[256];
  int t = threadIdx.x;
  int base = blockIdx.x * 1024 + t * 4;
  int v[4];
#pragma unroll
  for (int j = 0; j < 4; ++j) v[j] = (base + j < n) ? in[base + j] : 0;
  int tsum = v[0] + v[1] + v[2] + v[3];
  sh[t] = tsum;
  __syncthreads();
  for (int o = 1; o < 256; o <<= 1) {
    int add = (t >= o) ? sh[t - o] : 0;
    __syncthreads();
    sh[t] += add;
    __syncthreads();
  }
  int run = sh[t] - tsum + bsumx[blockIdx.x];
#pragma unroll
  for (int j = 0; j < 4; ++j) {
    if (base + j < n) out[base + j] = run;
    run += v[j];
  }
}

// ---------------- fill: atomic-free, pass-partitioned by segment range ----------------
__global__ void unisage_fill(const int* __restrict__ nid, const int* __restrict__ eid,
                             const unsigned int* __restrict__ rank,
                             const int* __restrict__ off,
                             int* __restrict__ csr_e, int* __restrict__ csr_n) {
  const int R = (NSEG + FILL_P - 1) / FILL_P;  // 18750
  int pass = blockIdx.x / FILL_B;
  int i = (blockIdx.x % FILL_B) * 256 + threadIdx.x;
  if (i >= NZ) return;
  int lo = pass * R, hi = lo + R;
  int e = eid[i], v = nid[i];
  unsigned r = rank[i];
  if (e >= lo && e < hi) csr_e[off[e] + (int)(r & 0xffffu)] = v;
  int s = NE + v;
  if (s >= lo && s < hi) csr_n[off[s] + (int)(r >> 16) - NZ] = e;
}

// ---------------- segment aggregations (one 64-lane wave per segment, bf16 gather) ----
__global__ void unisage_edge_agg(const unsigned short* __restrict__ xb,
                                 const int* __restrict__ csr_e,
                                 const int* __restrict__ off, const int* __restrict__ cnt,
                                 unsigned short* __restrict__ m01b) {
  int w = (blockIdx.x * 256 + threadIdx.x) >> 6;  // edge id
  int lane = threadIdx.x & 63;
  if (w >= NE) return;
  int beg = off[w];
  int end = beg + cnt[w];
  float ax = 0.f, ay = 0.f;
  for (int base = beg; base < end; base += 64) {
    int m = min(64, end - base);
    int idx = (lane < m) ? csr_e[base + lane] : 0;
    int j = 0;
    for (; j + 1 < m; j += 2) {
      int n0 = __shfl(idx, j, 64);
      int n1 = __shfl(idx, j + 1, 64);
      ushort2 a = *(const ushort2*)(xb + (size_t)n0 * D + lane * 2);
      ushort2 b = *(const ushort2*)(xb + (size_t)n1 * D + lane * 2);
      ax += bf2f(a.x) + bf2f(b.x);
      ay += bf2f(a.y) + bf2f(b.y);
    }
    if (j < m) {
      int n0 = __shfl(idx, j, 64);
      ushort2 a = *(const ushort2*)(xb + (size_t)n0 * D + lane * 2);
      ax += bf2f(a.x);
      ay += bf2f(a.y);
    }
  }
  ushort2 o; o.x = f2bf(ax); o.y = f2bf(ay);
  *(ushort2*)(m01b + (size_t)w * D + lane * 2) = o;
}

__global__ void unisage_node_agg(const unsigned short* __restrict__ xb,
                                 const unsigned short* __restrict__ m01b,
                                 const int* __restrict__ csr_n,
                                 const int* __restrict__ off, const int* __restrict__ cnt,
                                 float* __restrict__ out) {
  int w = (blockIdx.x * 256 + threadIdx.x) >> 6;  // node id
  int lane = threadIdx.x & 63;
  if (w >= NN) return;
  int deg = cnt[NE + w];
  int beg = off[NE + w] - NZ;
  int end = beg + deg;
  float ax = 0.f, ay = 0.f;
  for (int base = beg; base < end; base += 64) {
    int m = min(64, end - base);
    int idx = (lane < m) ? csr_n[base + lane] : 0;
    int j = 0;
    for (; j + 1 < m; j += 2) {
      int e0 = __shfl(idx, j, 64);
      int e1 = __shfl(idx, j + 1, 64);
      ushort2 a = *(const ushort2*)(m01b + (size_t)e0 * D + lane * 2);
      ushort2 b = *(const ushort2*)(m01b + (size_t)e1 * D + lane * 2);
      ax += bf2f(a.x) + bf2f(b.x);
      ay += bf2f(a.y) + bf2f(b.y);
    }
    if (j < m) {
      int e0 = __shfl(idx, j, 64);
      ushort2 a = *(const ushort2*)(m01b + (size_t)e0 * D + lane * 2);
      ax += bf2f(a.x);
      ay += bf2f(a.y);
    }
  }
  float inv = 1.0f / fmaxf((float)deg, 1.0f);
  ushort2 xr = *(const ushort2*)(xb + (size_t)w * D + lane * 2);
  float2 o;
  o.x = bf2f(xr.x) + ax * inv;
  o.y = bf2f(xr.y) + ay * inv;
  *(float2*)(out + (size_t)w * D + lane * 2) = o;
}

extern "C" void kernel_launch(void* const* d_in, const int* in_sizes, int n_in,
                              void* d_out, int out_size, void* d_ws, size_t ws_size,
                              hipStream_t stream) {
  const float* x0   = (const float*)d_in[0];
  const float* W    = (const float*)d_in[1];
  const float* bias = (const float*)d_in[2];
  const int* nid    = (const int*)d_in[3];
  const int* eid    = (const int*)d_in[4];
  float* out = (float*)d_out;

  // workspace layout (all 4B-aligned)
  unsigned short* xb   = (unsigned short*)d_ws;           // NN*D bf16 (25.6 MB)
  unsigned short* m01b = xb + (size_t)NN * D;             // NE*D bf16 (12.8 MB)
  int* cnt   = (int*)(m01b + (size_t)NE * D);             // NSEG
  int* off   = cnt + 150016;                              // NSEG
  unsigned int* rank = (unsigned int*)(off + 150016);     // NZ
  int* csr_e = (int*)(rank + NZ);                         // NZ
  int* csr_n = csr_e + NZ;                                // NZ
  int* bsum  = csr_n + NZ;                                // 256
  int* bsumx = bsum + 256;                                // 256

  hipMemsetAsync(cnt, 0, NSEG * sizeof(int), stream);

  unisage_gemm_mfma<<<(NN + 127) / 128, 256, 0, stream>>>(x0, W, bias, xb);

  unisage_hist_rank<<<NZ / 256, 256, 0, stream>>>(nid, eid, cnt, rank);

  const int nb = (NSEG + 1023) / 1024;  // 147
  unisage_scan_k1<<<nb, 256, 0, stream>>>(cnt, bsum, NSEG);
  unisage_scan_k2<<<1, 256, 0, stream>>>(bsum, bsumx, nb);
  unisage_scan_k3<<<nb, 256, 0, stream>>>(cnt, bsumx, off, NSEG);

  unisage_fill<<<FILL_P * FILL_B, 256, 0, stream>>>(nid, eid, rank, off, csr_e, csr_n);

  unisage_edge_agg<<<(NE * 64) / 256, 256, 0, stream>>>(xb, csr_e, off, cnt, m01b);
  unisage_node_agg<<<(NN * 64) / 256, 256, 0, stream>>>(xb, m01b, csr_n, off, cnt, out);
}

// Round 4
// 223.189 us; speedup vs baseline: 1.8532x; 1.0443x over previous
//
#include <hip/hip_runtime.h>
#include <hip/hip_bf16.h>

#define NN 100000   // nodes
#define NE 50000    // edges
#define NZ 800000   // incidences
#define D  128
#define NSEG (NE + NN)   // 150000
#define FILL_P 4         // fill passes (segment-range partitions)
#define FILL_B 782       // blocks per pass = ceil(NZ/4/256)

typedef __bf16 bf16x8 __attribute__((ext_vector_type(8)));
typedef float f32x4 __attribute__((ext_vector_type(4)));

static __device__ __forceinline__ unsigned short f2bf(float f) {
  union { float f; unsigned u; } v; v.f = f;
  unsigned r = (v.u + 0x7FFFu + ((v.u >> 16) & 1u)) >> 16;  // RNE
  return (unsigned short)r;
}
static __device__ __forceinline__ float bf2f(unsigned short h) {
  union { unsigned u; float f; } v; v.u = ((unsigned)h) << 16;
  return v.f;
}

// ---------------- GEMM via MFMA: xb = bf16(x0 @ W.T + b) ----------------
__global__ __launch_bounds__(256) void unisage_gemm_mfma(const float* __restrict__ x0,
                                                         const float* __restrict__ W,
                                                         const float* __restrict__ bias,
                                                         unsigned short* __restrict__ xb) {
  __shared__ __bf16 Wl[128][136];
  const int t = threadIdx.x;
#pragma unroll
  for (int i = 0; i < 16; ++i) {
    int idx = i * 1024 + t * 4;
    int dout = idx >> 7;
    int k = idx & 127;
    float4 wv = *(const float4*)(W + idx);
    Wl[dout][k + 0] = (__bf16)wv.x;
    Wl[dout][k + 1] = (__bf16)wv.y;
    Wl[dout][k + 2] = (__bf16)wv.z;
    Wl[dout][k + 3] = (__bf16)wv.w;
  }
  __syncthreads();

  const int wave = t >> 6;
  const int lane = t & 63;
  const int lr = lane & 15;
  const int lg = lane >> 4;
  const int rowbase = blockIdx.x * 128 + wave * 32;

  f32x4 acc[2][8] = {};

#pragma unroll
  for (int ks = 0; ks < 4; ++ks) {
    const int k0 = ks * 32 + lg * 8;
    bf16x8 b[8];
#pragma unroll
    for (int cf = 0; cf < 8; ++cf)
      b[cf] = *(const bf16x8*)&Wl[cf * 16 + lr][k0];
#pragma unroll
    for (int rf = 0; rf < 2; ++rf) {
      int row = rowbase + rf * 16 + lr;
      row = row < NN ? row : NN - 1;
      const float* src = x0 + (size_t)row * D + k0;
      float4 f0 = *(const float4*)(src);
      float4 f1 = *(const float4*)(src + 4);
      bf16x8 a;
      a[0] = (__bf16)f0.x; a[1] = (__bf16)f0.y;
      a[2] = (__bf16)f0.z; a[3] = (__bf16)f0.w;
      a[4] = (__bf16)f1.x; a[5] = (__bf16)f1.y;
      a[6] = (__bf16)f1.z; a[7] = (__bf16)f1.w;
#pragma unroll
      for (int cf = 0; cf < 8; ++cf)
        acc[rf][cf] = __builtin_amdgcn_mfma_f32_16x16x32_bf16(a, b[cf], acc[rf][cf], 0, 0, 0);
    }
  }

#pragma unroll
  for (int cf = 0; cf < 8; ++cf) {
    float bv = bias[cf * 16 + lr];
#pragma unroll
    for (int rf = 0; rf < 2; ++rf) {
#pragma unroll
      for (int r = 0; r < 4; ++r) {
        int row = rowbase + rf * 16 + lg * 4 + r;
        if (row < NN)
          xb[(size_t)row * D + cf * 16 + lr] = f2bf(acc[rf][cf][r] + bv);
      }
    }
  }
}

// ---------------- histogram + rank: 8 items/thread, 16 atomics in flight --------------
__global__ void unisage_hist_rank(const int* __restrict__ nid, const int* __restrict__ eid,
                                  int* __restrict__ cnt, unsigned int* __restrict__ rank) {
  int base = (blockIdx.x * 256 + threadIdx.x) * 8;
  if (base >= NZ) return;
  int4 ea = *(const int4*)(eid + base);
  int4 eb = *(const int4*)(eid + base + 4);
  int4 na = *(const int4*)(nid + base);
  int4 nb = *(const int4*)(nid + base + 4);
  int e[8] = {ea.x, ea.y, ea.z, ea.w, eb.x, eb.y, eb.z, eb.w};
  int v[8] = {na.x, na.y, na.z, na.w, nb.x, nb.y, nb.z, nb.w};
  unsigned re[8], rn[8];
#pragma unroll
  for (int j = 0; j < 8; ++j) re[j] = (unsigned)atomicAdd(&cnt[e[j]], 1);
#pragma unroll
  for (int j = 0; j < 8; ++j) rn[j] = (unsigned)atomicAdd(&cnt[NE + v[j]], 1);
  uint4 r0, r1;
  r0.x = (re[0] & 0xffffu) | (rn[0] << 16);
  r0.y = (re[1] & 0xffffu) | (rn[1] << 16);
  r0.z = (re[2] & 0xffffu) | (rn[2] << 16);
  r0.w = (re[3] & 0xffffu) | (rn[3] << 16);
  r1.x = (re[4] & 0xffffu) | (rn[4] << 16);
  r1.y = (re[5] & 0xffffu) | (rn[5] << 16);
  r1.z = (re[6] & 0xffffu) | (rn[6] << 16);
  r1.w = (re[7] & 0xffffu) | (rn[7] << 16);
  *(uint4*)(rank + base) = r0;
  *(uint4*)(rank + base + 4) = r1;
}

// ---------------- scans ----------------
__global__ void unisage_scan_k1(const int* __restrict__ in, int* __restrict__ bsum, int n) {
  __shared__ int sh[256];
  int t = threadIdx.x;
  int base = blockIdx.x * 1024 + t * 4;
  int s = 0;
#pragma unroll
  for (int j = 0; j < 4; ++j)
    if (base + j < n) s += in[base + j];
  sh[t] = s;
  __syncthreads();
  for (int o = 128; o > 0; o >>= 1) {
    if (t < o) sh[t] += sh[t + o];
    __syncthreads();
  }
  if (t == 0) bsum[blockIdx.x] = sh[0];
}

__global__ void unisage_scan_k2(const int* __restrict__ bsum, int* __restrict__ bsumx, int nb) {
  __shared__ int sh[256];
  int t = threadIdx.x;
  int v = (t < nb) ? bsum[t] : 0;
  sh[t] = v;
  __syncthreads();
  for (int o = 1; o < 256; o <<= 1) {
    int add = (t >= o) ? sh[t - o] : 0;
    __syncthreads();
    sh[t] += add;
    __syncthreads();
  }
  if (t < nb) bsumx[t] = sh[t] - v;  // exclusive
}

__global__ void unisage_scan_k3(const int* __restrict__ in, const int* __restrict__ bsumx,
                                int* __restrict__ out, int n) {
  __shared__ int sh[256];
  int t = threadIdx.x;
  int base = blockIdx.x * 1024 + t * 4;
  int v[4];
#pragma unroll
  for (int j = 0; j < 4; ++j) v[j] = (base + j < n) ? in[base + j] : 0;
  int tsum = v[0] + v[1] + v[2] + v[3];
  sh[t] = tsum;
  __syncthreads();
  for (int o = 1; o < 256; o <<= 1) {
    int add = (t >= o) ? sh[t - o] : 0;
    __syncthreads();
    sh[t] += add;
    __syncthreads();
  }
  int run = sh[t] - tsum + bsumx[blockIdx.x];
#pragma unroll
  for (int j = 0; j < 4; ++j) {
    if (base + j < n) out[base + j] = run;
    run += v[j];
  }
}

// ---------------- fill: atomic-free, pass-partitioned, 4 items/thread ----------------
__global__ void unisage_fill(const int* __restrict__ nid, const int* __restrict__ eid,
                             const unsigned int* __restrict__ rank,
                             const int* __restrict__ off,
                             int* __restrict__ csr_e, int* __restrict__ csr_n) {
  const int R = (NSEG + FILL_P - 1) / FILL_P;  // 37500
  int pass = blockIdx.x / FILL_B;
  int base = ((blockIdx.x % FILL_B) * 256 + threadIdx.x) * 4;
  if (base >= NZ) return;
  int lo = pass * R, hi = lo + R;
  int4 e4 = *(const int4*)(eid + base);
  int4 n4 = *(const int4*)(nid + base);
  uint4 r4 = *(const uint4*)(rank + base);
  int e[4] = {e4.x, e4.y, e4.z, e4.w};
  int v[4] = {n4.x, n4.y, n4.z, n4.w};
  unsigned r[4] = {r4.x, r4.y, r4.z, r4.w};
#pragma unroll
  for (int j = 0; j < 4; ++j) {
    if (e[j] >= lo && e[j] < hi) csr_e[off[e[j]] + (int)(r[j] & 0xffffu)] = v[j];
    int s = NE + v[j];
    if (s >= lo && s < hi) csr_n[off[s] + (int)(r[j] >> 16) - NZ] = e[j];
  }
}

// ---------------- segment aggregations (one wave per segment, 4-deep gather) ---------
__global__ void unisage_edge_agg(const unsigned short* __restrict__ xb,
                                 const int* __restrict__ csr_e,
                                 const int* __restrict__ off, const int* __restrict__ cnt,
                                 unsigned short* __restrict__ m01b) {
  int w = (blockIdx.x * 256 + threadIdx.x) >> 6;  // edge id
  int lane = threadIdx.x & 63;
  if (w >= NE) return;
  int beg = off[w];
  int end = beg + cnt[w];
  float ax = 0.f, ay = 0.f;
  for (int base = beg; base < end; base += 64) {
    int m = min(64, end - base);
    int idx = (lane < m) ? csr_e[base + lane] : 0;
    int j = 0;
    for (; j + 3 < m; j += 4) {
      int n0 = __shfl(idx, j, 64);
      int n1 = __shfl(idx, j + 1, 64);
      int n2 = __shfl(idx, j + 2, 64);
      int n3 = __shfl(idx, j + 3, 64);
      ushort2 a = *(const ushort2*)(xb + (size_t)n0 * D + lane * 2);
      ushort2 b = *(const ushort2*)(xb + (size_t)n1 * D + lane * 2);
      ushort2 c = *(const ushort2*)(xb + (size_t)n2 * D + lane * 2);
      ushort2 d = *(const ushort2*)(xb + (size_t)n3 * D + lane * 2);
      ax += (bf2f(a.x) + bf2f(b.x)) + (bf2f(c.x) + bf2f(d.x));
      ay += (bf2f(a.y) + bf2f(b.y)) + (bf2f(c.y) + bf2f(d.y));
    }
    for (; j < m; ++j) {
      int n0 = __shfl(idx, j, 64);
      ushort2 a = *(const ushort2*)(xb + (size_t)n0 * D + lane * 2);
      ax += bf2f(a.x);
      ay += bf2f(a.y);
    }
  }
  ushort2 o; o.x = f2bf(ax); o.y = f2bf(ay);
  *(ushort2*)(m01b + (size_t)w * D + lane * 2) = o;
}

__global__ void unisage_node_agg(const unsigned short* __restrict__ xb,
                                 const unsigned short* __restrict__ m01b,
                                 const int* __restrict__ csr_n,
                                 const int* __restrict__ off, const int* __restrict__ cnt,
                                 float* __restrict__ out) {
  int w = (blockIdx.x * 256 + threadIdx.x) >> 6;  // node id
  int lane = threadIdx.x & 63;
  if (w >= NN) return;
  int deg = cnt[NE + w];
  int beg = off[NE + w] - NZ;
  int end = beg + deg;
  float ax = 0.f, ay = 0.f;
  for (int base = beg; base < end; base += 64) {
    int m = min(64, end - base);
    int idx = (lane < m) ? csr_n[base + lane] : 0;
    int j = 0;
    for (; j + 3 < m; j += 4) {
      int e0 = __shfl(idx, j, 64);
      int e1 = __shfl(idx, j + 1, 64);
      int e2 = __shfl(idx, j + 2, 64);
      int e3 = __shfl(idx, j + 3, 64);
      ushort2 a = *(const ushort2*)(m01b + (size_t)e0 * D + lane * 2);
      ushort2 b = *(const ushort2*)(m01b + (size_t)e1 * D + lane * 2);
      ushort2 c = *(const ushort2*)(m01b + (size_t)e2 * D + lane * 2);
      ushort2 d = *(const ushort2*)(m01b + (size_t)e3 * D + lane * 2);
      ax += (bf2f(a.x) + bf2f(b.x)) + (bf2f(c.x) + bf2f(d.x));
      ay += (bf2f(a.y) + bf2f(b.y)) + (bf2f(c.y) + bf2f(d.y));
    }
    for (; j < m; ++j) {
      int e0 = __shfl(idx, j, 64);
      ushort2 a = *(const ushort2*)(m01b + (size_t)e0 * D + lane * 2);
      ax += bf2f(a.x);
      ay += bf2f(a.y);
    }
  }
  float inv = 1.0f / fmaxf((float)deg, 1.0f);
  ushort2 xr = *(const ushort2*)(xb + (size_t)w * D + lane * 2);
  float2 o;
  o.x = bf2f(xr.x) + ax * inv;
  o.y = bf2f(xr.y) + ay * inv;
  *(float2*)(out + (size_t)w * D + lane * 2) = o;
}

extern "C" void kernel_launch(void* const* d_in, const int* in_sizes, int n_in,
                              void* d_out, int out_size, void* d_ws, size_t ws_size,
                              hipStream_t stream) {
  const float* x0   = (const float*)d_in[0];
  const float* W    = (const float*)d_in[1];
  const float* bias = (const float*)d_in[2];
  const int* nid    = (const int*)d_in[3];
  const int* eid    = (const int*)d_in[4];
  float* out = (float*)d_out;

  unsigned short* xb   = (unsigned short*)d_ws;           // NN*D bf16 (25.6 MB)
  unsigned short* m01b = xb + (size_t)NN * D;             // NE*D bf16 (12.8 MB)
  int* cnt   = (int*)(m01b + (size_t)NE * D);             // NSEG
  int* off   = cnt + 150016;                              // NSEG
  unsigned int* rank = (unsigned int*)(off + 150016);     // NZ
  int* csr_e = (int*)(rank + NZ);                         // NZ
  int* csr_n = csr_e + NZ;                                // NZ
  int* bsum  = csr_n + NZ;                                // 256
  int* bsumx = bsum + 256;                                // 256

  hipMemsetAsync(cnt, 0, NSEG * sizeof(int), stream);

  unisage_gemm_mfma<<<(NN + 127) / 128, 256, 0, stream>>>(x0, W, bias, xb);

  unisage_hist_rank<<<(NZ / 8 + 255) / 256, 256, 0, stream>>>(nid, eid, cnt, rank);

  const int nb = (NSEG + 1023) / 1024;  // 147
  unisage_scan_k1<<<nb, 256, 0, stream>>>(cnt, bsum, NSEG);
  unisage_scan_k2<<<1, 256, 0, stream>>>(bsum, bsumx, nb);
  unisage_scan_k3<<<nb, 256, 0, stream>>>(cnt, bsumx, off, NSEG);

  unisage_fill<<<FILL_P * FILL_B, 256, 0, stream>>>(nid, eid, rank, off, csr_e, csr_n);

  unisage_edge_agg<<<(NE * 64) / 256, 256, 0, stream>>>(xb, csr_e, off, cnt, m01b);
  unisage_node_agg<<<(NN * 64) / 256, 256, 0, stream>>>(xb, m01b, csr_n, off, cnt, out);
}

// Round 5
// 211.125 us; speedup vs baseline: 1.9591x; 1.0571x over previous
//
#include <hip/hip_runtime.h>
#include <hip/hip_bf16.h>

#define NN 100000   // nodes
#define NE 50000    // edges
#define NZ 800000   // incidences
#define D  128
#define NSEG (NE + NN)   // 150000
#define FILL_P 4         // fill passes (segment-range partitions)
#define FILL_B 782       // blocks per pass = ceil(NZ/4/256)
#define G_GEMM 782       // (NN+127)/128
#define G_HIST 391       // ceil(NZ/8/256)

typedef __bf16 bf16x8 __attribute__((ext_vector_type(8)));
typedef float f32x4 __attribute__((ext_vector_type(4)));

static __device__ __forceinline__ unsigned short f2bf(float f) {
  union { float f; unsigned u; } v; v.f = f;
  unsigned r = (v.u + 0x7FFFu + ((v.u >> 16) & 1u)) >> 16;  // RNE
  return (unsigned short)r;
}
static __device__ __forceinline__ float bf2f(unsigned short h) {
  union { unsigned u; float f; } v; v.u = ((unsigned)h) << 16;
  return v.f;
}

// ---------------- fused: GEMM (blocks [0,G_GEMM)) + hist_rank (rest) ----------------
// The two are independent; hist is atomic-pipe-bound (~850 GB/s of packets), gemm is
// HBM/MFMA-bound -> they overlap on different resources.
__global__ __launch_bounds__(256) void unisage_gemm_hist(const float* __restrict__ x0,
                                                         const float* __restrict__ W,
                                                         const float* __restrict__ bias,
                                                         unsigned short* __restrict__ xb,
                                                         const int* __restrict__ nid,
                                                         const int* __restrict__ eid,
                                                         int* __restrict__ cnt,
                                                         unsigned int* __restrict__ rank) {
  __shared__ __bf16 Wl[128][136];
  if (blockIdx.x < G_GEMM) {
    const int t = threadIdx.x;
#pragma unroll
    for (int i = 0; i < 16; ++i) {
      int idx = i * 1024 + t * 4;
      int dout = idx >> 7;
      int k = idx & 127;
      float4 wv = *(const float4*)(W + idx);
      Wl[dout][k + 0] = (__bf16)wv.x;
      Wl[dout][k + 1] = (__bf16)wv.y;
      Wl[dout][k + 2] = (__bf16)wv.z;
      Wl[dout][k + 3] = (__bf16)wv.w;
    }
    __syncthreads();

    const int wave = t >> 6;
    const int lane = t & 63;
    const int lr = lane & 15;
    const int lg = lane >> 4;
    const int rowbase = blockIdx.x * 128 + wave * 32;

    f32x4 acc[2][8] = {};

#pragma unroll
    for (int ks = 0; ks < 4; ++ks) {
      const int k0 = ks * 32 + lg * 8;
      bf16x8 b[8];
#pragma unroll
      for (int cf = 0; cf < 8; ++cf)
        b[cf] = *(const bf16x8*)&Wl[cf * 16 + lr][k0];
#pragma unroll
      for (int rf = 0; rf < 2; ++rf) {
        int row = rowbase + rf * 16 + lr;
        row = row < NN ? row : NN - 1;
        const float* src = x0 + (size_t)row * D + k0;
        float4 f0 = *(const float4*)(src);
        float4 f1 = *(const float4*)(src + 4);
        bf16x8 a;
        a[0] = (__bf16)f0.x; a[1] = (__bf16)f0.y;
        a[2] = (__bf16)f0.z; a[3] = (__bf16)f0.w;
        a[4] = (__bf16)f1.x; a[5] = (__bf16)f1.y;
        a[6] = (__bf16)f1.z; a[7] = (__bf16)f1.w;
#pragma unroll
        for (int cf = 0; cf < 8; ++cf)
          acc[rf][cf] = __builtin_amdgcn_mfma_f32_16x16x32_bf16(a, b[cf], acc[rf][cf], 0, 0, 0);
      }
    }

#pragma unroll
    for (int cf = 0; cf < 8; ++cf) {
      float bv = bias[cf * 16 + lr];
#pragma unroll
      for (int rf = 0; rf < 2; ++rf) {
#pragma unroll
        for (int r = 0; r < 4; ++r) {
          int row = rowbase + rf * 16 + lg * 4 + r;
          if (row < NN)
            xb[(size_t)row * D + cf * 16 + lr] = f2bf(acc[rf][cf][r] + bv);
        }
      }
    }
  } else {
    // ---- hist_rank: 8 items/thread ----
    int base = ((blockIdx.x - G_GEMM) * 256 + threadIdx.x) * 8;
    if (base >= NZ) return;
    int4 ea = *(const int4*)(eid + base);
    int4 eb = *(const int4*)(eid + base + 4);
    int4 na = *(const int4*)(nid + base);
    int4 nb = *(const int4*)(nid + base + 4);
    int e[8] = {ea.x, ea.y, ea.z, ea.w, eb.x, eb.y, eb.z, eb.w};
    int v[8] = {na.x, na.y, na.z, na.w, nb.x, nb.y, nb.z, nb.w};
    unsigned re[8], rn[8];
#pragma unroll
    for (int j = 0; j < 8; ++j) re[j] = (unsigned)atomicAdd(&cnt[e[j]], 1);
#pragma unroll
    for (int j = 0; j < 8; ++j) rn[j] = (unsigned)atomicAdd(&cnt[NE + v[j]], 1);
    uint4 r0, r1;
    r0.x = (re[0] & 0xffffu) | (rn[0] << 16);
    r0.y = (re[1] & 0xffffu) | (rn[1] << 16);
    r0.z = (re[2] & 0xffffu) | (rn[2] << 16);
    r0.w = (re[3] & 0xffffu) | (rn[3] << 16);
    r1.x = (re[4] & 0xffffu) | (rn[4] << 16);
    r1.y = (re[5] & 0xffffu) | (rn[5] << 16);
    r1.z = (re[6] & 0xffffu) | (rn[6] << 16);
    r1.w = (re[7] & 0xffffu) | (rn[7] << 16);
    *(uint4*)(rank + base) = r0;
    *(uint4*)(rank + base + 4) = r1;
  }
}

// ---------------- scans ----------------
__global__ void unisage_scan_k1(const int* __restrict__ in, int* __restrict__ bsum, int n) {
  __shared__ int sh[256];
  int t = threadIdx.x;
  int base = blockIdx.x * 1024 + t * 4;
  int s = 0;
#pragma unroll
  for (int j = 0; j < 4; ++j)
    if (base + j < n) s += in[base + j];
  sh[t] = s;
  __syncthreads();
  for (int o = 128; o > 0; o >>= 1) {
    if (t < o) sh[t] += sh[t + o];
    __syncthreads();
  }
  if (t == 0) bsum[blockIdx.x] = sh[0];
}

// k3 with the k2 (block-sum scan) folded in: every block locally scans bsum[0..nb)
__global__ void unisage_scan_k3(const int* __restrict__ in, const int* __restrict__ bsum,
                                int* __restrict__ out, int n, int nb) {
  __shared__ int sh[256];
  int t = threadIdx.x;
  // local inclusive scan of block sums
  int bv = (t < nb) ? bsum[t] : 0;
  sh[t] = bv;
  __syncthreads();
  for (int o = 1; o < 256; o <<= 1) {
    int add = (t >= o) ? sh[t - o] : 0;
    __syncthreads();
    sh[t] += add;
    __syncthreads();
  }
  int bbase = (blockIdx.x == 0) ? 0 : sh[blockIdx.x - 1];
  __syncthreads();

  int base = blockIdx.x * 1024 + t * 4;
  int v[4];
#pragma unroll
  for (int j = 0; j < 4; ++j) v[j] = (base + j < n) ? in[base + j] : 0;
  int tsum = v[0] + v[1] + v[2] + v[3];
  sh[t] = tsum;
  __syncthreads();
  for (int o = 1; o < 256; o <<= 1) {
    int add = (t >= o) ? sh[t - o] : 0;
    __syncthreads();
    sh[t] += add;
    __syncthreads();
  }
  int run = sh[t] - tsum + bbase;
#pragma unroll
  for (int j = 0; j < 4; ++j) {
    if (base + j < n) out[base + j] = run;
    run += v[j];
  }
}

// ---------------- fill: atomic-free, pass-partitioned, 4 items/thread ----------------
__global__ void unisage_fill(const int* __restrict__ nid, const int* __restrict__ eid,
                             const unsigned int* __restrict__ rank,
                             const int* __restrict__ off,
                             int* __restrict__ csr_e, int* __restrict__ csr_n) {
  const int R = (NSEG + FILL_P - 1) / FILL_P;  // 37500
  int pass = blockIdx.x / FILL_B;
  int base = ((blockIdx.x % FILL_B) * 256 + threadIdx.x) * 4;
  if (base >= NZ) return;
  int lo = pass * R, hi = lo + R;
  int4 e4 = *(const int4*)(eid + base);
  int4 n4 = *(const int4*)(nid + base);
  uint4 r4 = *(const uint4*)(rank + base);
  int e[4] = {e4.x, e4.y, e4.z, e4.w};
  int v[4] = {n4.x, n4.y, n4.z, n4.w};
  unsigned r[4] = {r4.x, r4.y, r4.z, r4.w};
#pragma unroll
  for (int j = 0; j < 4; ++j) {
    if (e[j] >= lo && e[j] < hi) csr_e[off[e[j]] + (int)(r[j] & 0xffffu)] = v[j];
    int s = NE + v[j];
    if (s >= lo && s < hi) csr_n[off[s] + (int)(r[j] >> 16) - NZ] = e[j];
  }
}

// ---------------- segment aggregations: 4 rows/instr, 16B per lane ----------------
// lane = quad*16 + sl; quad (0..3) picks row within a group of 4; lane loads 8 bf16
// (cols sl*8..sl*8+7). Quad partials combined with 2 shfl_xor levels at the end.
#define QRED(x) { x += __shfl_xor(x, 16, 64); x += __shfl_xor(x, 32, 64); }

__global__ void unisage_edge_agg(const unsigned short* __restrict__ xb,
                                 const int* __restrict__ csr_e,
                                 const int* __restrict__ off, const int* __restrict__ cnt,
                                 unsigned short* __restrict__ m01b) {
  int w = (blockIdx.x * 256 + threadIdx.x) >> 6;  // edge id
  int lane = threadIdx.x & 63;
  if (w >= NE) return;
  int quad = lane >> 4;
  int sl = lane & 15;
  int beg = off[w];
  int deg = cnt[w];
  int end = beg + deg;
  float a0 = 0, a1 = 0, a2 = 0, a3 = 0, a4 = 0, a5 = 0, a6 = 0, a7 = 0;
  for (int base = beg; base < end; base += 64) {
    int m = min(64, end - base);
    int idx = (lane < m) ? csr_e[base + lane] : 0;
    int iters = (m + 3) >> 2;
    for (int jj = 0; jj < iters; ++jj) {
      int p = 4 * jj + quad;
      int r = __shfl(idx, p, 64);
      if (p < m) {
        uint4 vv = *(const uint4*)(xb + (size_t)r * D + sl * 8);
        a0 += bf2f((unsigned short)(vv.x & 0xffffu)); a1 += bf2f((unsigned short)(vv.x >> 16));
        a2 += bf2f((unsigned short)(vv.y & 0xffffu)); a3 += bf2f((unsigned short)(vv.y >> 16));
        a4 += bf2f((unsigned short)(vv.z & 0xffffu)); a5 += bf2f((unsigned short)(vv.z >> 16));
        a6 += bf2f((unsigned short)(vv.w & 0xffffu)); a7 += bf2f((unsigned short)(vv.w >> 16));
      }
    }
  }
  QRED(a0) QRED(a1) QRED(a2) QRED(a3) QRED(a4) QRED(a5) QRED(a6) QRED(a7)
  if (quad == 0) {
    uint4 o;
    o.x = (unsigned)f2bf(a0) | ((unsigned)f2bf(a1) << 16);
    o.y = (unsigned)f2bf(a2) | ((unsigned)f2bf(a3) << 16);
    o.z = (unsigned)f2bf(a4) | ((unsigned)f2bf(a5) << 16);
    o.w = (unsigned)f2bf(a6) | ((unsigned)f2bf(a7) << 16);
    *(uint4*)(m01b + (size_t)w * D + sl * 8) = o;
  }
}

__global__ void unisage_node_agg(const unsigned short* __restrict__ xb,
                                 const unsigned short* __restrict__ m01b,
                                 const int* __restrict__ csr_n,
                                 const int* __restrict__ off, const int* __restrict__ cnt,
                                 float* __restrict__ out) {
  int w = (blockIdx.x * 256 + threadIdx.x) >> 6;  // node id
  int lane = threadIdx.x & 63;
  if (w >= NN) return;
  int quad = lane >> 4;
  int sl = lane & 15;
  int deg = cnt[NE + w];
  int beg = off[NE + w] - NZ;
  int end = beg + deg;
  float a0 = 0, a1 = 0, a2 = 0, a3 = 0, a4 = 0, a5 = 0, a6 = 0, a7 = 0;
  for (int base = beg; base < end; base += 64) {
    int m = min(64, end - base);
    int idx = (lane < m) ? csr_n[base + lane] : 0;
    int iters = (m + 3) >> 2;
    for (int jj = 0; jj < iters; ++jj) {
      int p = 4 * jj + quad;
      int r = __shfl(idx, p, 64);
      if (p < m) {
        uint4 vv = *(const uint4*)(m01b + (size_t)r * D + sl * 8);
        a0 += bf2f((unsigned short)(vv.x & 0xffffu)); a1 += bf2f((unsigned short)(vv.x >> 16));
        a2 += bf2f((unsigned short)(vv.y & 0xffffu)); a3 += bf2f((unsigned short)(vv.y >> 16));
        a4 += bf2f((unsigned short)(vv.z & 0xffffu)); a5 += bf2f((unsigned short)(vv.z >> 16));
        a6 += bf2f((unsigned short)(vv.w & 0xffffu)); a7 += bf2f((unsigned short)(vv.w >> 16));
      }
    }
  }
  QRED(a0) QRED(a1) QRED(a2) QRED(a3) QRED(a4) QRED(a5) QRED(a6) QRED(a7)
  if (quad == 0) {
    float inv = 1.0f / fmaxf((float)deg, 1.0f);
    uint4 xr = *(const uint4*)(xb + (size_t)w * D + sl * 8);
    float4 o0, o1;
    o0.x = bf2f((unsigned short)(xr.x & 0xffffu)) + a0 * inv;
    o0.y = bf2f((unsigned short)(xr.x >> 16))     + a1 * inv;
    o0.z = bf2f((unsigned short)(xr.y & 0xffffu)) + a2 * inv;
    o0.w = bf2f((unsigned short)(xr.y >> 16))     + a3 * inv;
    o1.x = bf2f((unsigned short)(xr.z & 0xffffu)) + a4 * inv;
    o1.y = bf2f((unsigned short)(xr.z >> 16))     + a5 * inv;
    o1.z = bf2f((unsigned short)(xr.w & 0xffffu)) + a6 * inv;
    o1.w = bf2f((unsigned short)(xr.w >> 16))     + a7 * inv;
    *(float4*)(out + (size_t)w * D + sl * 8) = o0;
    *(float4*)(out + (size_t)w * D + sl * 8 + 4) = o1;
  }
}

extern "C" void kernel_launch(void* const* d_in, const int* in_sizes, int n_in,
                              void* d_out, int out_size, void* d_ws, size_t ws_size,
                              hipStream_t stream) {
  const float* x0   = (const float*)d_in[0];
  const float* W    = (const float*)d_in[1];
  const float* bias = (const float*)d_in[2];
  const int* nid    = (const int*)d_in[3];
  const int* eid    = (const int*)d_in[4];
  float* out = (float*)d_out;

  unsigned short* xb   = (unsigned short*)d_ws;           // NN*D bf16 (25.6 MB)
  unsigned short* m01b = xb + (size_t)NN * D;             // NE*D bf16 (12.8 MB)
  int* cnt   = (int*)(m01b + (size_t)NE * D);             // NSEG
  int* off   = cnt + 150016;                              // NSEG
  unsigned int* rank = (unsigned int*)(off + 150016);     // NZ
  int* csr_e = (int*)(rank + NZ);                         // NZ
  int* csr_n = csr_e + NZ;                                // NZ
  int* bsum  = csr_n + NZ;                                // 256

  hipMemsetAsync(cnt, 0, NSEG * sizeof(int), stream);

  unisage_gemm_hist<<<G_GEMM + G_HIST, 256, 0, stream>>>(x0, W, bias, xb, nid, eid, cnt, rank);

  const int nb = (NSEG + 1023) / 1024;  // 147
  unisage_scan_k1<<<nb, 256, 0, stream>>>(cnt, bsum, NSEG);
  unisage_scan_k3<<<nb, 256, 0, stream>>>(cnt, bsum, off, NSEG, nb);

  unisage_fill<<<FILL_P * FILL_B, 256, 0, stream>>>(nid, eid, rank, off, csr_e, csr_n);

  unisage_edge_agg<<<(NE * 64) / 256, 256, 0, stream>>>(xb, csr_e, off, cnt, m01b);
  unisage_node_agg<<<(NN * 64) / 256, 256, 0, stream>>>(xb, m01b, csr_n, off, cnt, out);
}